// Round 9
// baseline (99.157 us; speedup 1.0000x reference)
//
#include <hip/hip_runtime.h>

#define NQ   6
#define DIM  64
#define OH   63
#define HH   128
#define CIN  4
#define NB   128
#define PSTR 80   // P row stride in shorts (160B = 16B-aligned)

typedef __attribute__((ext_vector_type(8))) short short8;
typedef __attribute__((ext_vector_type(4))) float f32x4;

__device__ __forceinline__ unsigned bf16_rne_u(float f) {
    unsigned u = __builtin_bit_cast(unsigned, f);
    return (u + 0x7fffu + ((u >> 16) & 1u)) >> 16;   // round-nearest-even
}

#if __has_builtin(__builtin_amdgcn_cvt_pk_bf16_f32)
__device__ __forceinline__ unsigned pk_bf16(float a, float b) {
    typedef __attribute__((ext_vector_type(2))) __bf16 bf16x2_t;
    bf16x2_t v = __builtin_amdgcn_cvt_pk_bf16_f32(a, b);
    return __builtin_bit_cast(unsigned, v);
}
#else
__device__ __forceinline__ unsigned pk_bf16(float a, float b) {
    return bf16_rne_u(a) | (bf16_rne_u(b) << 16);
}
#endif

// ---------------------------------------------------------------------------
// Build: one block per basis column col; 64 lanes = 64 amplitudes.
// Lanes 0..11 own the 12 gate matrices (one transcendental pass); broadcast
// via shfl. Lane i ends holding U[i][col]; scatters Re->frag row i,
// Im->frag row 64+i of the wfrag layout:
//   frag f (0..15): mt=f>>1, t=f&1; lane l holds
//   A[m = mt*16 + (l&15)][k = t*32 + (l>>4)*8 + j], j=0..7.
// Frags 16..17: S-matrix A-fragments (lane-only; identical writes, benign).
// ---------------------------------------------------------------------------
__global__ __launch_bounds__(64) void build_wfrag(const float* __restrict__ wts,
                                                  short* __restrict__ wfrag) {
    const int i   = threadIdx.x;
    const int col = blockIdx.x;

    const int g = (i < 12) ? i : 0;
    const float phi = wts[g * 3 + 0];
    const float th  = wts[g * 3 + 1];
    const float om  = wts[g * 3 + 2];
    const float hc = cosf(0.5f * th);
    const float hs = sinf(0.5f * th);
    const float ap = -0.5f * (phi + om);
    const float am = -0.5f * (phi - om);
    // U00=(a,b) U01=(-c,d) U10=(c,d) U11=(a,-b)
    const float ga = cosf(ap) * hc;
    const float gb = sinf(ap) * hc;
    const float gc = cosf(am) * hs;
    const float gd = sinf(am) * hs;

    float2 amp = make_float2(i == col ? 1.0f : 0.0f, 0.0f);

    for (int rep = 0; rep < 2; ++rep) {
        for (int l = 0; l < 2; ++l) {
            for (int w = 0; w < NQ; ++w) {
                const int src = l * 6 + w;
                const float a = __shfl(ga, src, 64);
                const float b = __shfl(gb, src, 64);
                const float c = __shfl(gc, src, 64);
                const float d = __shfl(gd, src, 64);
                const int p = 5 - w;
                const int bbit = (i >> p) & 1;
                const float px = __shfl_xor(amp.x, 1 << p, 64);
                const float py = __shfl_xor(amp.y, 1 << p, 64);
                const float uax = a;
                const float uay = bbit ? -b : b;
                const float ubx = bbit ? c : -c;
                const float uby = d;
                float2 na;
                na.x = uax * amp.x - uay * amp.y + ubx * px - uby * py;
                na.y = uax * amp.y + uay * amp.x + ubx * py + uby * px;
                amp = na;
            }
            const int r = (l == 0) ? 1 : 2;   // l % (NQ-1) + 1
            for (int w = 0; w < NQ; ++w) {
                const int pc = 5 - w;
                const int pt = 5 - ((w + r) % NQ);
                const int src = i ^ (((i >> pc) & 1) << pt);
                const float nx = __shfl(amp.x, src, 64);
                const float ny = __shfl(amp.y, src, 64);
                amp = make_float2(nx, ny);
            }
        }
    }

    const int t    = col >> 5;
    const int quad = (col >> 3) & 3;
    const int j    = col & 7;
    const int lre  = quad * 16 + (i & 15);
    const int fre  = ((i >> 4)    ) * 2 + t;   // Re: rows 0..63
    const int fim  = ((i >> 4) + 4) * 2 + t;   // Im: rows 64..127
    wfrag[(fre * 64 + lre) * 8 + j] = (short)bf16_rne_u(amp.x);
    wfrag[(fim * 64 + lre) * 8 + j] = (short)bf16_rne_u(amp.y);

    // ---- S fragments (frags 16..17): rows 0..5 Pauli-Z signs, 6 ones ----
    {
        const int n  = i & 15;
        const int qq = i >> 4;
#pragma unroll
        for (int tt = 0; tt < 2; ++tt) {
            short8 v;
#pragma unroll
            for (int jj = 0; jj < 8; ++jj) {
                const int k = tt * 32 + qq * 8 + jj;
                unsigned short s;
                if (n < 6)       s = ((k >> (5 - n)) & 1) ? 0xBF80 : 0x3F80;
                else if (n == 6) s = 0x3F80;
                else             s = 0;
                v[jj] = (short)s;
            }
            ((int4*)wfrag)[(16 + tt) * 64 + i] = __builtin_bit_cast(int4, v);
        }
    }
}

// ---------------------------------------------------------------------------
// Main: grid 8064 = one block per (b,oy) row; wave wv handles the single
// chunk ox = wv*16 + n. All 4 waves share the row's 16 x-lines (L1 reuse).
// Shortest-possible wave: loads (features + W frags, all in flight at wave
// start) -> pack -> G = W·F (16 MFMA) -> P -> LDS -> Z = S·P (2 MFMA) ->
// normalize/store. No prefetch/rotate; VGPR slim -> 4 blocks/CU.
// ---------------------------------------------------------------------------
__global__ __launch_bounds__(256, 4) void qconv_mfma(const float* __restrict__ x,
                                                     const short* __restrict__ wfrag,
                                                     float* __restrict__ out) {
    __shared__ __align__(16) short sP[4][16 * PSTR];    // 10 KiB

    const int tid  = threadIdx.x;
    const int lane = tid & 63;
    const int wv   = tid >> 6;
    const int n    = lane & 15;
    const int qq   = lane >> 4;

    const int row = blockIdx.x;            // 0..8063
    const int b   = row / OH;
    const int oy  = row - b * OH;

    // ---- x row pointers for this lane's 4 (c,kh) rows ----
    const int c0  = qq >> 1;
    const int kh0 = (qq & 1) * 2;
    const float* xb  = x + (size_t)b * CIN * HH * HH;
    const float* r00 = xb + ((c0    ) * HH + 2 * oy + kh0    ) * HH;
    const float* r01 = xb + ((c0    ) * HH + 2 * oy + kh0 + 1) * HH;
    const float* r10 = xb + ((c0 + 2) * HH + 2 * oy + kh0    ) * HH;
    const float* r11 = xb + ((c0 + 2) * HH + 2 * oy + kh0 + 1) * HH;

    // ---- feature loads for this wave's chunk (issued first, HBM) ----
    const int ox  = wv * 16 + n;
    const int oxl = min(ox, OH - 1);       // clamps only wv=3,n=15
    const int fo  = 2 * oxl;
    float2 cur[8];
    cur[0] = *(const float2*)(r00 + fo);
    cur[1] = *(const float2*)(r00 + fo + 2);
    cur[2] = *(const float2*)(r01 + fo);
    cur[3] = *(const float2*)(r01 + fo + 2);
    cur[4] = *(const float2*)(r10 + fo);
    cur[5] = *(const float2*)(r10 + fo + 2);
    cur[6] = *(const float2*)(r11 + fo);
    cur[7] = *(const float2*)(r11 + fo + 2);

    // ---- W + S fragments (18 coalesced int4 loads, L2-resident) ----
    short8 wfr[8][2], sfr[2];
    {
        const int4* wp = (const int4*)wfrag;
#pragma unroll
        for (int mt = 0; mt < 8; ++mt)
#pragma unroll
            for (int t = 0; t < 2; ++t)
                wfr[mt][t] = __builtin_bit_cast(short8, wp[(mt * 2 + t) * 64 + lane]);
#pragma unroll
        for (int t = 0; t < 2; ++t)
            sfr[t] = __builtin_bit_cast(short8, wp[(16 + t) * 64 + lane]);
    }

    // ---- pack features into B fragments ----
    uint4 u0, u1;
    u0.x = pk_bf16(cur[0].x, cur[0].y);  u0.y = pk_bf16(cur[1].x, cur[1].y);
    u0.z = pk_bf16(cur[2].x, cur[2].y);  u0.w = pk_bf16(cur[3].x, cur[3].y);
    u1.x = pk_bf16(cur[4].x, cur[4].y);  u1.y = pk_bf16(cur[5].x, cur[5].y);
    u1.z = pk_bf16(cur[6].x, cur[6].y);  u1.w = pk_bf16(cur[7].x, cur[7].y);
    const short8 bf0 = __builtin_bit_cast(short8, u0);
    const short8 bf1 = __builtin_bit_cast(short8, u1);

    // ---- G = W · F (16 MFMA) ----
    f32x4 acc[8];
#pragma unroll
    for (int mt = 0; mt < 8; ++mt) acc[mt] = (f32x4){0.f, 0.f, 0.f, 0.f};
#pragma unroll
    for (int mt = 0; mt < 8; ++mt) {
        acc[mt] = __builtin_amdgcn_mfma_f32_16x16x32_bf16(wfr[mt][0], bf0, acc[mt], 0, 0, 0);
        acc[mt] = __builtin_amdgcn_mfma_f32_16x16x32_bf16(wfr[mt][1], bf1, acc[mt], 0, 0, 0);
    }

    // ---- P = Gre^2 + Gim^2 -> bf16 (RNE) -> LDS (wave-private) ----
    short* myP = sP[wv];
#pragma unroll
    for (int mt = 0; mt < 4; ++mt) {
        const float p0 = acc[mt][0] * acc[mt][0] + acc[mt + 4][0] * acc[mt + 4][0];
        const float p1 = acc[mt][1] * acc[mt][1] + acc[mt + 4][1] * acc[mt + 4][1];
        const float p2 = acc[mt][2] * acc[mt][2] + acc[mt + 4][2] * acc[mt + 4][2];
        const float p3 = acc[mt][3] * acc[mt][3] + acc[mt + 4][3] * acc[mt + 4][3];
        const unsigned w0 = pk_bf16(p0, p1);
        const unsigned w1 = pk_bf16(p2, p3);
        *((uint2*)(((unsigned*)myP) + n * (PSTR / 2) + mt * 8 + qq * 2)) =
            make_uint2(w0, w1);
    }

    // ---- Z = S · P ----
    const short8 p0f = *(const short8*)(myP + n * PSTR + qq * 8);
    const short8 p1f = *(const short8*)(myP + n * PSTR + 32 + qq * 8);
    f32x4 c2 = (f32x4){0.f, 0.f, 0.f, 0.f};
    c2 = __builtin_amdgcn_mfma_f32_16x16x32_bf16(sfr[0], p0f, c2, 0, 0, 0);
    c2 = __builtin_amdgcn_mfma_f32_16x16x32_bf16(sfr[1], p1f, c2, 0, 0, 0);

    // ---- normalize + store: Z row q = qq*4 + reg; norm = row 6 ----
    const float norm = __shfl(c2[2], 16 + n, 64);
    const float inv  = 1.0f / norm;
    if (ox < OH) {
        float* ob = out + ((size_t)b * NQ * OH + oy) * OH + ox;
        if (qq == 0) {
#pragma unroll
            for (int r = 0; r < 4; ++r)
                __builtin_nontemporal_store(c2[r] * inv, ob + (size_t)r * (OH * OH));
        } else if (qq == 1) {
            __builtin_nontemporal_store(c2[0] * inv, ob + (size_t)4 * (OH * OH));
            __builtin_nontemporal_store(c2[1] * inv, ob + (size_t)5 * (OH * OH));
        }
    }
}

extern "C" void kernel_launch(void* const* d_in, const int* in_sizes, int n_in,
                              void* d_out, int out_size, void* d_ws, size_t ws_size,
                              hipStream_t stream) {
    const float* x   = (const float*)d_in[0];   // (128, 4, 128, 128) f32
    const float* wts = (const float*)d_in[1];   // (2, 6, 3) f32
    float* out = (float*)d_out;                 // (128, 6, 63, 63) f32
    short* wfrag = (short*)d_ws;                // 18 frags * 1 KiB

    build_wfrag<<<64, 64, 0, stream>>>(wts, wfrag);
    qconv_mfma<<<NB * OH, 256, 0, stream>>>(x, wfrag, out);
}

// Round 10
// 95.729 us; speedup vs baseline: 1.0358x; 1.0358x over previous
//
#include <hip/hip_runtime.h>

#define NQ   6
#define DIM  64
#define OH   63
#define HH   128
#define CIN  4
#define NB   128
#define PSTR 80   // P row stride in shorts (160B = 16B-aligned)

typedef __attribute__((ext_vector_type(8))) short short8;
typedef __attribute__((ext_vector_type(4))) float f32x4;

__device__ __forceinline__ unsigned bf16_rne_u(float f) {
    unsigned u = __builtin_bit_cast(unsigned, f);
    return (u + 0x7fffu + ((u >> 16) & 1u)) >> 16;   // round-nearest-even
}

#if __has_builtin(__builtin_amdgcn_cvt_pk_bf16_f32)
__device__ __forceinline__ unsigned pk_bf16(float a, float b) {
    typedef __attribute__((ext_vector_type(2))) __bf16 bf16x2_t;
    bf16x2_t v = __builtin_amdgcn_cvt_pk_bf16_f32(a, b);
    return __builtin_bit_cast(unsigned, v);
}
#else
__device__ __forceinline__ unsigned pk_bf16(float a, float b) {
    return bf16_rne_u(a) | (bf16_rne_u(b) << 16);
}
#endif

// ---------------------------------------------------------------------------
// Build: one block per basis column col; 64 lanes = 64 amplitudes.
// Lanes 0..11 own the 12 gate matrices (one transcendental pass); broadcast
// via shfl. Lane i ends holding U[i][col]; scatters Re->frag row i,
// Im->frag row 64+i of the wfrag layout:
//   frag f (0..15): mt=f>>1, t=f&1; lane l holds
//   A[m = mt*16 + (l&15)][k = t*32 + (l>>4)*8 + j], j=0..7.
// Frags 16..17: S-matrix A-fragments (lane-only; identical writes, benign).
// ---------------------------------------------------------------------------
__global__ __launch_bounds__(64) void build_wfrag(const float* __restrict__ wts,
                                                  short* __restrict__ wfrag) {
    const int i   = threadIdx.x;
    const int col = blockIdx.x;

    const int g = (i < 12) ? i : 0;
    const float phi = wts[g * 3 + 0];
    const float th  = wts[g * 3 + 1];
    const float om  = wts[g * 3 + 2];
    const float hc = cosf(0.5f * th);
    const float hs = sinf(0.5f * th);
    const float ap = -0.5f * (phi + om);
    const float am = -0.5f * (phi - om);
    // U00=(a,b) U01=(-c,d) U10=(c,d) U11=(a,-b)
    const float ga = cosf(ap) * hc;
    const float gb = sinf(ap) * hc;
    const float gc = cosf(am) * hs;
    const float gd = sinf(am) * hs;

    float2 amp = make_float2(i == col ? 1.0f : 0.0f, 0.0f);

    for (int rep = 0; rep < 2; ++rep) {
        for (int l = 0; l < 2; ++l) {
            for (int w = 0; w < NQ; ++w) {
                const int src = l * 6 + w;
                const float a = __shfl(ga, src, 64);
                const float b = __shfl(gb, src, 64);
                const float c = __shfl(gc, src, 64);
                const float d = __shfl(gd, src, 64);
                const int p = 5 - w;
                const int bbit = (i >> p) & 1;
                const float px = __shfl_xor(amp.x, 1 << p, 64);
                const float py = __shfl_xor(amp.y, 1 << p, 64);
                const float uax = a;
                const float uay = bbit ? -b : b;
                const float ubx = bbit ? c : -c;
                const float uby = d;
                float2 na;
                na.x = uax * amp.x - uay * amp.y + ubx * px - uby * py;
                na.y = uax * amp.y + uay * amp.x + ubx * py + uby * px;
                amp = na;
            }
            const int r = (l == 0) ? 1 : 2;   // l % (NQ-1) + 1
            for (int w = 0; w < NQ; ++w) {
                const int pc = 5 - w;
                const int pt = 5 - ((w + r) % NQ);
                const int src = i ^ (((i >> pc) & 1) << pt);
                const float nx = __shfl(amp.x, src, 64);
                const float ny = __shfl(amp.y, src, 64);
                amp = make_float2(nx, ny);
            }
        }
    }

    const int t    = col >> 5;
    const int quad = (col >> 3) & 3;
    const int j    = col & 7;
    const int lre  = quad * 16 + (i & 15);
    const int fre  = ((i >> 4)    ) * 2 + t;   // Re: rows 0..63
    const int fim  = ((i >> 4) + 4) * 2 + t;   // Im: rows 64..127
    wfrag[(fre * 64 + lre) * 8 + j] = (short)bf16_rne_u(amp.x);
    wfrag[(fim * 64 + lre) * 8 + j] = (short)bf16_rne_u(amp.y);

    // ---- S fragments (frags 16..17): rows 0..5 Pauli-Z signs, 6 ones ----
    {
        const int n  = i & 15;
        const int qq = i >> 4;
#pragma unroll
        for (int tt = 0; tt < 2; ++tt) {
            short8 v;
#pragma unroll
            for (int jj = 0; jj < 8; ++jj) {
                const int k = tt * 32 + qq * 8 + jj;
                unsigned short s;
                if (n < 6)       s = ((k >> (5 - n)) & 1) ? 0xBF80 : 0x3F80;
                else if (n == 6) s = 0x3F80;
                else             s = 0;
                v[jj] = (short)s;
            }
            ((int4*)wfrag)[(16 + tt) * 64 + i] = __builtin_bit_cast(int4, v);
        }
    }
}

// ---------------------------------------------------------------------------
// Main: grid 16128 single-wave blocks (wave-granular scheduling). Block ->
// unit = (bid&7)*2016 + (bid>>3): XCD-contiguous row ranges so the stride-2
// kh-overlap re-read of x hits the XCD-local L2. Each wave owns one (b,oy)
// row-half = 2 chunks of 16 samples; ALL loads (32 F float2 + 18 W/S int4)
// hoisted to wave start -> one latency exposure, then straight-line compute.
//  G = W·F (16 MFMA), P = Gre^2+Gim^2 -> LDS -> Z = S·P (2 MFMA),
//  z_q = Z[q][n] / Z[6][n]  (row 6 of S = ones -> ||f||^2, U unitary).
// ---------------------------------------------------------------------------
__global__ __launch_bounds__(64, 3) void qconv_mfma(const float* __restrict__ x,
                                                    const short* __restrict__ wfrag,
                                                    float* __restrict__ out) {
    __shared__ __align__(16) short sP[16 * PSTR];    // 2.5 KiB, wave-private

    const int lane = threadIdx.x;
    const int n    = lane & 15;
    const int qq   = lane >> 4;

    const int bid   = blockIdx.x;
    const int unit  = (bid & 7) * 2016 + (bid >> 3);   // 0..16127
    const int row   = unit >> 1;                       // 0..8063
    const int half2 = (unit & 1) * 2;                  // chunk base 0 or 2
    const int b     = row / OH;
    const int oy    = row - b * OH;

    // ---- x row pointers for this lane's 4 (c,kh) rows ----
    const int c0  = qq >> 1;
    const int kh0 = (qq & 1) * 2;
    const float* xb  = x + (size_t)b * CIN * HH * HH;
    const float* r00 = xb + ((c0    ) * HH + 2 * oy + kh0    ) * HH;
    const float* r01 = xb + ((c0    ) * HH + 2 * oy + kh0 + 1) * HH;
    const float* r10 = xb + ((c0 + 2) * HH + 2 * oy + kh0    ) * HH;
    const float* r11 = xb + ((c0 + 2) * HH + 2 * oy + kh0 + 1) * HH;

#define LOAD8(dst, chg_)                                                     \
    {                                                                        \
        const int oxl_ = min((chg_) * 16 + n, OH - 1);                       \
        const int fo_  = 2 * oxl_;                                           \
        dst[0] = *(const float2*)(r00 + fo_);                                \
        dst[1] = *(const float2*)(r00 + fo_ + 2);                            \
        dst[2] = *(const float2*)(r01 + fo_);                                \
        dst[3] = *(const float2*)(r01 + fo_ + 2);                            \
        dst[4] = *(const float2*)(r10 + fo_);                                \
        dst[5] = *(const float2*)(r10 + fo_ + 2);                            \
        dst[6] = *(const float2*)(r11 + fo_);                                \
        dst[7] = *(const float2*)(r11 + fo_ + 2);                            \
    }

    // ---- hoist ALL loads: both chunks' features + W/S fragments ----
    float2 cur[8], nxt[8];
    LOAD8(cur, half2)
    LOAD8(nxt, half2 + 1)

    short8 wfr[8][2], sfr[2];
    {
        const int4* wp = (const int4*)wfrag;
#pragma unroll
        for (int mt = 0; mt < 8; ++mt)
#pragma unroll
            for (int t = 0; t < 2; ++t)
                wfr[mt][t] = __builtin_bit_cast(short8, wp[(mt * 2 + t) * 64 + lane]);
#pragma unroll
        for (int t = 0; t < 2; ++t)
            sfr[t] = __builtin_bit_cast(short8, wp[(16 + t) * 64 + lane]);
    }

#pragma unroll
    for (int ch = 0; ch < 2; ++ch) {
        const float2* f = (ch == 0) ? cur : nxt;

        // ---- pack features into B fragments ----
        uint4 u0, u1;
        u0.x = pk_bf16(f[0].x, f[0].y);  u0.y = pk_bf16(f[1].x, f[1].y);
        u0.z = pk_bf16(f[2].x, f[2].y);  u0.w = pk_bf16(f[3].x, f[3].y);
        u1.x = pk_bf16(f[4].x, f[4].y);  u1.y = pk_bf16(f[5].x, f[5].y);
        u1.z = pk_bf16(f[6].x, f[6].y);  u1.w = pk_bf16(f[7].x, f[7].y);
        const short8 bf0 = __builtin_bit_cast(short8, u0);
        const short8 bf1 = __builtin_bit_cast(short8, u1);

        // ---- G = W · F (16 MFMA) ----
        f32x4 acc[8];
#pragma unroll
        for (int mt = 0; mt < 8; ++mt) acc[mt] = (f32x4){0.f, 0.f, 0.f, 0.f};
#pragma unroll
        for (int mt = 0; mt < 8; ++mt) {
            acc[mt] = __builtin_amdgcn_mfma_f32_16x16x32_bf16(wfr[mt][0], bf0, acc[mt], 0, 0, 0);
            acc[mt] = __builtin_amdgcn_mfma_f32_16x16x32_bf16(wfr[mt][1], bf1, acc[mt], 0, 0, 0);
        }

        // ---- P = Gre^2 + Gim^2 -> bf16 (RNE) -> LDS (wave-private) ----
#pragma unroll
        for (int mt = 0; mt < 4; ++mt) {
            const float p0 = acc[mt][0] * acc[mt][0] + acc[mt + 4][0] * acc[mt + 4][0];
            const float p1 = acc[mt][1] * acc[mt][1] + acc[mt + 4][1] * acc[mt + 4][1];
            const float p2 = acc[mt][2] * acc[mt][2] + acc[mt + 4][2] * acc[mt + 4][2];
            const float p3 = acc[mt][3] * acc[mt][3] + acc[mt + 4][3] * acc[mt + 4][3];
            const unsigned w0 = pk_bf16(p0, p1);
            const unsigned w1 = pk_bf16(p2, p3);
            *((uint2*)(((unsigned*)sP) + n * (PSTR / 2) + mt * 8 + qq * 2)) =
                make_uint2(w0, w1);
        }

        // ---- Z = S · P ----
        const short8 p0f = *(const short8*)(sP + n * PSTR + qq * 8);
        const short8 p1f = *(const short8*)(sP + n * PSTR + 32 + qq * 8);
        f32x4 c2 = (f32x4){0.f, 0.f, 0.f, 0.f};
        c2 = __builtin_amdgcn_mfma_f32_16x16x32_bf16(sfr[0], p0f, c2, 0, 0, 0);
        c2 = __builtin_amdgcn_mfma_f32_16x16x32_bf16(sfr[1], p1f, c2, 0, 0, 0);

        // ---- normalize + store: Z row q = qq*4 + reg; norm = row 6 ----
        const float norm = __shfl(c2[2], 16 + n, 64);
        const float inv  = 1.0f / norm;
        const int ox = (half2 + ch) * 16 + n;
        if (ox < OH) {
            float* ob = out + ((size_t)b * NQ * OH + oy) * OH + ox;
            if (qq == 0) {
#pragma unroll
                for (int r = 0; r < 4; ++r)
                    __builtin_nontemporal_store(c2[r] * inv, ob + (size_t)r * (OH * OH));
            } else if (qq == 1) {
                __builtin_nontemporal_store(c2[0] * inv, ob + (size_t)4 * (OH * OH));
                __builtin_nontemporal_store(c2[1] * inv, ob + (size_t)5 * (OH * OH));
            }
        }
    }
#undef LOAD8
}

extern "C" void kernel_launch(void* const* d_in, const int* in_sizes, int n_in,
                              void* d_out, int out_size, void* d_ws, size_t ws_size,
                              hipStream_t stream) {
    const float* x   = (const float*)d_in[0];   // (128, 4, 128, 128) f32
    const float* wts = (const float*)d_in[1];   // (2, 6, 3) f32
    float* out = (float*)d_out;                 // (128, 6, 63, 63) f32
    short* wfrag = (short*)d_ws;                // 18 frags * 1 KiB

    build_wfrag<<<64, 64, 0, stream>>>(wts, wfrag);
    qconv_mfma<<<NB * OH * 2, 64, 0, stream>>>(x, wfrag, out);
}

// Round 11
// 94.347 us; speedup vs baseline: 1.0510x; 1.0146x over previous
//
#include <hip/hip_runtime.h>

#define NQ   6
#define DIM  64
#define OH   63
#define HH   128
#define CIN  4
#define NB   128
#define PSTR 80   // P row stride in shorts (160B = 16B-aligned)

typedef __attribute__((ext_vector_type(8))) short short8;
typedef __attribute__((ext_vector_type(4))) float f32x4;

__device__ __forceinline__ unsigned bf16_rne_u(float f) {
    unsigned u = __builtin_bit_cast(unsigned, f);
    return (u + 0x7fffu + ((u >> 16) & 1u)) >> 16;   // round-nearest-even
}

#if __has_builtin(__builtin_amdgcn_cvt_pk_bf16_f32)
__device__ __forceinline__ unsigned pk_bf16(float a, float b) {
    typedef __attribute__((ext_vector_type(2))) __bf16 bf16x2_t;
    bf16x2_t v = __builtin_amdgcn_cvt_pk_bf16_f32(a, b);
    return __builtin_bit_cast(unsigned, v);
}
#else
__device__ __forceinline__ unsigned pk_bf16(float a, float b) {
    return bf16_rne_u(a) | (bf16_rne_u(b) << 16);
}
#endif

// ---------------------------------------------------------------------------
// Build: one block per basis column col; 64 lanes = 64 amplitudes.
// Lanes 0..11 own the 12 gate matrices (one transcendental pass); broadcast
// via shfl. Lane i ends holding U[i][col]; scatters Re->frag row i,
// Im->frag row 64+i of the wfrag layout:
//   frag f (0..15): mt=f>>1, t=f&1; lane l holds
//   A[m = mt*16 + (l&15)][k = t*32 + (l>>4)*8 + j], j=0..7.
// Frags 16..17: S-matrix A-fragments (lane-only; identical writes, benign).
// ---------------------------------------------------------------------------
__global__ __launch_bounds__(64) void build_wfrag(const float* __restrict__ wts,
                                                  short* __restrict__ wfrag) {
    const int i   = threadIdx.x;
    const int col = blockIdx.x;

    const int g = (i < 12) ? i : 0;
    const float phi = wts[g * 3 + 0];
    const float th  = wts[g * 3 + 1];
    const float om  = wts[g * 3 + 2];
    const float hc = cosf(0.5f * th);
    const float hs = sinf(0.5f * th);
    const float ap = -0.5f * (phi + om);
    const float am = -0.5f * (phi - om);
    // U00=(a,b) U01=(-c,d) U10=(c,d) U11=(a,-b)
    const float ga = cosf(ap) * hc;
    const float gb = sinf(ap) * hc;
    const float gc = cosf(am) * hs;
    const float gd = sinf(am) * hs;

    float2 amp = make_float2(i == col ? 1.0f : 0.0f, 0.0f);

    for (int rep = 0; rep < 2; ++rep) {
        for (int l = 0; l < 2; ++l) {
            for (int w = 0; w < NQ; ++w) {
                const int src = l * 6 + w;
                const float a = __shfl(ga, src, 64);
                const float b = __shfl(gb, src, 64);
                const float c = __shfl(gc, src, 64);
                const float d = __shfl(gd, src, 64);
                const int p = 5 - w;
                const int bbit = (i >> p) & 1;
                const float px = __shfl_xor(amp.x, 1 << p, 64);
                const float py = __shfl_xor(amp.y, 1 << p, 64);
                const float uax = a;
                const float uay = bbit ? -b : b;
                const float ubx = bbit ? c : -c;
                const float uby = d;
                float2 na;
                na.x = uax * amp.x - uay * amp.y + ubx * px - uby * py;
                na.y = uax * amp.y + uay * amp.x + ubx * py + uby * px;
                amp = na;
            }
            const int r = (l == 0) ? 1 : 2;   // l % (NQ-1) + 1
            for (int w = 0; w < NQ; ++w) {
                const int pc = 5 - w;
                const int pt = 5 - ((w + r) % NQ);
                const int src = i ^ (((i >> pc) & 1) << pt);
                const float nx = __shfl(amp.x, src, 64);
                const float ny = __shfl(amp.y, src, 64);
                amp = make_float2(nx, ny);
            }
        }
    }

    const int t    = col >> 5;
    const int quad = (col >> 3) & 3;
    const int j    = col & 7;
    const int lre  = quad * 16 + (i & 15);
    const int fre  = ((i >> 4)    ) * 2 + t;   // Re: rows 0..63
    const int fim  = ((i >> 4) + 4) * 2 + t;   // Im: rows 64..127
    wfrag[(fre * 64 + lre) * 8 + j] = (short)bf16_rne_u(amp.x);
    wfrag[(fim * 64 + lre) * 8 + j] = (short)bf16_rne_u(amp.y);

    // ---- S fragments (frags 16..17): rows 0..5 Pauli-Z signs, 6 ones ----
    {
        const int n  = i & 15;
        const int qq = i >> 4;
#pragma unroll
        for (int tt = 0; tt < 2; ++tt) {
            short8 v;
#pragma unroll
            for (int jj = 0; jj < 8; ++jj) {
                const int k = tt * 32 + qq * 8 + jj;
                unsigned short s;
                if (n < 6)       s = ((k >> (5 - n)) & 1) ? 0xBF80 : 0x3F80;
                else if (n == 6) s = 0x3F80;
                else             s = 0;
                v[jj] = (short)s;
            }
            ((int4*)wfrag)[(16 + tt) * 64 + i] = __builtin_bit_cast(int4, v);
        }
    }
}

// ---------------------------------------------------------------------------
// Main (measured-best R7 config): grid 4032; block -> (4 rows) x (half of ox
// range). Each wave owns one (b,oy) row-half = 2 chunks of 16 samples,
// depth-1 register software-pipeline on the feature loads.
//  B-fragments of F built directly from global: lane (qq,n) takes
//  F[k=qq*8+j][n] from x[b, c0(+2), 2oy+kh0(+1), 2ox .. 2ox+3].
//  G = W·F (16 MFMA), P = Gre^2+Gim^2 -> LDS -> Z = S·P (2 MFMA),
//  z_q = Z[q][n] / Z[6][n]  (row 6 of S = ones -> ||f||^2, U unitary).
// Config notes (bracketed by R6/R8/R9/R10 experiments):
//  - 2 chunks/wave beats 1 (99.2) and 4 (105.6)
//  - per-wave L2 W preload beats LDS staging (96.3)
//  - 4-wave blocks beat single-wave blocks (95.7)
// ---------------------------------------------------------------------------
__global__ __launch_bounds__(256, 3) void qconv_mfma(const float* __restrict__ x,
                                                     const short* __restrict__ wfrag,
                                                     float* __restrict__ out) {
    __shared__ __align__(16) short sP[4][16 * PSTR];   // 10 KiB

    const int tid  = threadIdx.x;
    const int lane = tid & 63;
    const int wv   = tid >> 6;
    const int n    = lane & 15;
    const int qq   = lane >> 4;

    const int bid   = blockIdx.x;
    const int row   = (bid >> 1) * 4 + wv;   // 0..8063
    const int half2 = (bid & 1) * 2;         // global chunk base (0 or 2)
    const int b     = row / OH;
    const int oy    = row - b * OH;

    // ---- x row pointers for this lane's 4 (c,kh) rows ----
    const int c0  = qq >> 1;
    const int kh0 = (qq & 1) * 2;
    const float* xb  = x + (size_t)b * CIN * HH * HH;
    const float* r00 = xb + ((c0    ) * HH + 2 * oy + kh0    ) * HH;
    const float* r01 = xb + ((c0    ) * HH + 2 * oy + kh0 + 1) * HH;
    const float* r10 = xb + ((c0 + 2) * HH + 2 * oy + kh0    ) * HH;
    const float* r11 = xb + ((c0 + 2) * HH + 2 * oy + kh0 + 1) * HH;

#define LOAD8(dst, chg_)                                                     \
    {                                                                        \
        const int oxl_ = min((chg_) * 16 + n, OH - 1);                       \
        const int fo_  = 2 * oxl_;                                           \
        dst[0] = *(const float2*)(r00 + fo_);                                \
        dst[1] = *(const float2*)(r00 + fo_ + 2);                            \
        dst[2] = *(const float2*)(r01 + fo_);                                \
        dst[3] = *(const float2*)(r01 + fo_ + 2);                            \
        dst[4] = *(const float2*)(r10 + fo_);                                \
        dst[5] = *(const float2*)(r10 + fo_ + 2);                            \
        dst[6] = *(const float2*)(r11 + fo_);                                \
        dst[7] = *(const float2*)(r11 + fo_ + 2);                            \
    }

    // prologue: loads for first chunk (in flight during W-frag preload)
    float2 cur[8];
    LOAD8(cur, half2)

    // ---- W fragments + S fragments (18 coalesced int4 loads, L2-resident)
    short8 wfr[8][2], sfr[2];
    {
        const int4* wp = (const int4*)wfrag;
#pragma unroll
        for (int mt = 0; mt < 8; ++mt)
#pragma unroll
            for (int t = 0; t < 2; ++t)
                wfr[mt][t] = __builtin_bit_cast(short8, wp[(mt * 2 + t) * 64 + lane]);
#pragma unroll
        for (int t = 0; t < 2; ++t)
            sfr[t] = __builtin_bit_cast(short8, wp[(16 + t) * 64 + lane]);
    }

    short* myP = sP[wv];

#pragma unroll
    for (int ch = 0; ch < 2; ++ch) {
        // ---- prefetch next chunk BEFORE consuming current (latency hiding)
        float2 nxt[8];
        if (ch < 1) LOAD8(nxt, half2 + 1)

        // ---- pack current features into B fragments ----
        uint4 u0, u1;
        u0.x = pk_bf16(cur[0].x, cur[0].y);  u0.y = pk_bf16(cur[1].x, cur[1].y);
        u0.z = pk_bf16(cur[2].x, cur[2].y);  u0.w = pk_bf16(cur[3].x, cur[3].y);
        u1.x = pk_bf16(cur[4].x, cur[4].y);  u1.y = pk_bf16(cur[5].x, cur[5].y);
        u1.z = pk_bf16(cur[6].x, cur[6].y);  u1.w = pk_bf16(cur[7].x, cur[7].y);
        const short8 bf0 = __builtin_bit_cast(short8, u0);
        const short8 bf1 = __builtin_bit_cast(short8, u1);

        // ---- G = W · F (16 MFMA) ----
        f32x4 acc[8];
#pragma unroll
        for (int mt = 0; mt < 8; ++mt) acc[mt] = (f32x4){0.f, 0.f, 0.f, 0.f};
#pragma unroll
        for (int mt = 0; mt < 8; ++mt) {
            acc[mt] = __builtin_amdgcn_mfma_f32_16x16x32_bf16(wfr[mt][0], bf0, acc[mt], 0, 0, 0);
            acc[mt] = __builtin_amdgcn_mfma_f32_16x16x32_bf16(wfr[mt][1], bf1, acc[mt], 0, 0, 0);
        }

        // ---- P = Gre^2 + Gim^2 -> bf16 (RNE) -> LDS (wave-private) ----
#pragma unroll
        for (int mt = 0; mt < 4; ++mt) {
            const float p0 = acc[mt][0] * acc[mt][0] + acc[mt + 4][0] * acc[mt + 4][0];
            const float p1 = acc[mt][1] * acc[mt][1] + acc[mt + 4][1] * acc[mt + 4][1];
            const float p2 = acc[mt][2] * acc[mt][2] + acc[mt + 4][2] * acc[mt + 4][2];
            const float p3 = acc[mt][3] * acc[mt][3] + acc[mt + 4][3] * acc[mt + 4][3];
            const unsigned w0 = pk_bf16(p0, p1);
            const unsigned w1 = pk_bf16(p2, p3);
            *((uint2*)(((unsigned*)myP) + n * (PSTR / 2) + mt * 8 + qq * 2)) =
                make_uint2(w0, w1);
        }

        // ---- Z = S · P ----
        const short8 p0f = *(const short8*)(myP + n * PSTR + qq * 8);
        const short8 p1f = *(const short8*)(myP + n * PSTR + 32 + qq * 8);
        f32x4 c2 = (f32x4){0.f, 0.f, 0.f, 0.f};
        c2 = __builtin_amdgcn_mfma_f32_16x16x32_bf16(sfr[0], p0f, c2, 0, 0, 0);
        c2 = __builtin_amdgcn_mfma_f32_16x16x32_bf16(sfr[1], p1f, c2, 0, 0, 0);

        // ---- normalize + store: Z row q = qq*4 + reg; norm = row 6 ----
        const float norm = __shfl(c2[2], 16 + n, 64);
        const float inv  = 1.0f / norm;
        const int ox = (half2 + ch) * 16 + n;
        if (ox < OH) {
            float* ob = out + ((size_t)b * NQ * OH + oy) * OH + ox;
            if (qq == 0) {
#pragma unroll
                for (int r = 0; r < 4; ++r)
                    __builtin_nontemporal_store(c2[r] * inv, ob + (size_t)r * (OH * OH));
            } else if (qq == 1) {
                __builtin_nontemporal_store(c2[0] * inv, ob + (size_t)4 * (OH * OH));
                __builtin_nontemporal_store(c2[1] * inv, ob + (size_t)5 * (OH * OH));
            }
        }

        // ---- rotate pipeline ----
        if (ch < 1) {
#pragma unroll
            for (int i = 0; i < 8; ++i) cur[i] = nxt[i];
        }
    }
#undef LOAD8
}

extern "C" void kernel_launch(void* const* d_in, const int* in_sizes, int n_in,
                              void* d_out, int out_size, void* d_ws, size_t ws_size,
                              hipStream_t stream) {
    const float* x   = (const float*)d_in[0];   // (128, 4, 128, 128) f32
    const float* wts = (const float*)d_in[1];   // (2, 6, 3) f32
    float* out = (float*)d_out;                 // (128, 6, 63, 63) f32
    short* wfrag = (short*)d_ws;                // 18 frags * 1 KiB

    build_wfrag<<<64, 64, 0, stream>>>(wts, wfrag);
    qconv_mfma<<<(NB * OH) / 2, 256, 0, stream>>>(x, wfrag, out);
}